// Round 14
// baseline (7028.333 us; speedup 1.0000x reference)
//
#include <hip/hip_runtime.h>
#include <hip/hip_bf16.h>
#include <cstdint>
#include <cstddef>

// LSTM_3624952398014 — R14: R8 protocol, minus self-inflicted serial prefix.
//  1. Raw LDS-only barriers (lgkmcnt(0)+s_barrier): __syncthreads' implicit
//     vmcnt(0) drain was serializing VMEM into each barrier; only LDS
//     visibility is needed.
//  2. x prefetched to registers one step ahead via PLAIN C++ load (safe
//     across back-edge; R9/R11/R12 corruption was asm-tied regs only).
//  3. Polls issued at loop top; they stay in flight through x-write, sync1
//     and the 4 x-MFMAs (barriers no longer drain VMEM).
// Exchange protocol unchanged from R8 (best, 3.92ms): tag16|bf16 words,
// global_atomic_swap publish, sc0sc1 polls, min-tree + partial re-poll,
// spin budget, rcp gate math. Geometry locked: 128 blk x 256 thr, 1 MFMA
// tile/wave, W in 80 VGPRs (R7/R10/R13 falsified all other geometries).
// Congestion falsified (R13 halved poll volume -> slower). Residual after
// this round = peer-publish skew.
// Layer 1 of the reference is dead code; out = relu(h_final(L0)) @ W_out^T + b.

#define B_ 64
#define T_ 2048
#define F_ 128
#define H_ 512

#define NBLK 128
#define NTHR 256

#define ACT_STRIDE 1280                 // 640 bf16 per act row
#define SMEM_SZ (16 * ACT_STRIDE)       // 20480 B
#define HSLOT (B_ * H_)                 // 32768 tagged u32 per slot

typedef __bf16 bf16;
typedef __bf16 bf16x4 __attribute__((ext_vector_type(4)));
typedef __bf16 bf16x8 __attribute__((ext_vector_type(8)));
typedef float f32x4 __attribute__((ext_vector_type(4)));
typedef unsigned int u32;
typedef u32 u32x2 __attribute__((ext_vector_type(2)));
typedef u32 u32x4 __attribute__((ext_vector_type(4)));

static __device__ __forceinline__ float sigm(float v) {
  return __builtin_amdgcn_rcpf(1.f + __expf(-v));
}
static __device__ __forceinline__ float tanh_f(float v) {
  float a = fminf(fabsf(v), 20.f);
  float e = __expf(-2.f * a);
  float t = 1.f - 2.f * e * __builtin_amdgcn_rcpf(1.f + e);
  return copysignf(t, v);
}
static __device__ __forceinline__ u32 bf16bits(float f) {
  bf16 b = (bf16)f;
  unsigned short us;
  __builtin_memcpy(&us, &b, 2);
  return (u32)us;
}
static __device__ __forceinline__ u32 min4(u32x4 v) {
  u32 a = v[0] < v[1] ? v[0] : v[1];
  u32 b = v[2] < v[3] ? v[2] : v[3];
  return a < b ? a : b;
}
// LDS-only barrier: waits LDS ops, does NOT drain VMEM (unlike __syncthreads).
static __device__ __forceinline__ void bar_lds() {
  asm volatile("s_waitcnt lgkmcnt(0)" ::: "memory");
  __builtin_amdgcn_s_barrier();
  __builtin_amdgcn_sched_barrier(0);
}

__global__ void __launch_bounds__(NTHR) prep_kernel(u32* hbuf) {
  int idx = blockIdx.x * blockDim.x + threadIdx.x;   // 256*256 = 65536 = 2*HSLOT
  if (idx < 2 * HSLOT) hbuf[idx] = 0u;               // both slots: tag 0, h = 0
}

// x [B][T][F] f32  ->  xbf [T][4 rg][16 row][128] bf16
__global__ void __launch_bounds__(NTHR) xconv_kernel(
    const float* __restrict__ x, bf16* __restrict__ xbf) {
  const int b = blockIdx.x;          // 0..63
  const int t0 = blockIdx.y * 256;   // grid.y = 8
  const int f2 = threadIdx.x & 63;   // 2 floats per thread
  const int tq = threadIdx.x >> 6;   // 0..3
  const int rg = b >> 4, row = b & 15;
  for (int i = 0; i < 64; ++i) {
    int t = t0 + i * 4 + tq;
    float2 xv = *(const float2*)(x + ((size_t)b * T_ + t) * F_ + 2 * f2);
    u32 w = bf16bits(xv.x) | (bf16bits(xv.y) << 16);
    *(u32*)((char*)xbf + ((((size_t)t * 4 + rg) * 16 + row) * 128 + 2 * f2) * 2) = w;
  }
}

__global__ void __launch_bounds__(NTHR, 1) lstm_kernel(
    const float* __restrict__ x,
    const float* __restrict__ Wih,
    const float* __restrict__ Whh,
    const float* __restrict__ bih,
    const float* __restrict__ bhh,
    u32* __restrict__ hbuf,        // [2][B_][H_] tagged u32
    float* __restrict__ hf32,      // [B_][H_] final h fp32
    const bf16* __restrict__ xbf)  // [T][4][16][128] bf16 or nullptr
{
  __shared__ __align__(16) char smem[SMEM_SZ];

  const int tid = threadIdx.x;
  const int bid = blockIdx.x;
  const int rg = bid >> 5;          // 0..3
  const int jg = bid & 31;          // 0..31
  const int row0 = rg * 16;
  const int j0 = jg * 16;

  const int lane = tid & 63;
  const int wave = tid >> 6;        // 0..3
  const int fr = lane & 15;
  const int kg = lane >> 4;         // 0..3

  // ---- one-time: W slice -> register A-fragments (1 tile/wave, 80 VGPR) ----
  bf16x8 wfrag[20];
  {
    const int G = (fr >> 2) * H_ + j0 + wave * 4 + (fr & 3);
    const float* sih = Wih + (size_t)G * F_;
    const float* shh = Whh + (size_t)G * H_;
    #pragma unroll
    for (int kk = 0; kk < 20; ++kk) {
      const float* s = (kk < 4) ? (sih + kk * 32 + kg * 8)
                                : (shh + (kk - 4) * 32 + kg * 8);
      float4 f0 = *(const float4*)s;
      float4 f1 = *(const float4*)(s + 4);
      bf16x8 w = { (bf16)f0.x, (bf16)f0.y, (bf16)f0.z, (bf16)f0.w,
                   (bf16)f1.x, (bf16)f1.y, (bf16)f1.z, (bf16)f1.w };
      wfrag[kk] = w;
    }
  }

  // per-lane cell (post-transpose): b = row0+fr, j = j0 + wave*4 + kg
  const int jcol = j0 + wave * 4 + kg;
  const float bi_ = bih[0 * H_ + jcol] + bhh[0 * H_ + jcol];
  const float bf_ = bih[1 * H_ + jcol] + bhh[1 * H_ + jcol];
  const float bg_ = bih[2 * H_ + jcol] + bhh[2 * H_ + jcol];
  const float bo_ = bih[3 * H_ + jcol] + bhh[3 * H_ + jcol];

  // poll/unpack ids
  const int prow = tid >> 4;        // 0..15
  const int pw = tid & 15;
  const int swz = (prow & 7) << 4;
  // f32-fallback x staging ids
  const int r0x = tid >> 5;
  const int c40 = tid & 31;
  const float* xp0 = x + (size_t)(row0 + r0x) * T_ * F_ + c40 * 4;
  const float* xp1 = x + (size_t)(row0 + r0x + 8) * T_ * F_ + c40 * 4;
  const int xw0 = r0x * ACT_STRIDE + ((8 * c40) ^ ((r0x & 7) << 4));
  const int xw1 = (r0x + 8) * ACT_STRIDE + ((8 * c40) ^ (((r0x + 8) & 7) << 4));
  // bf16 x staging ids (row = tid>>4, 16B seg = tid&15)
  const int xw = prow * ACT_STRIDE + ((pw * 16) ^ swz);
  const char* xsrc = (const char*)xbf + (size_t)rg * 4096 + tid * 16;

  const char* bbase = smem + fr * ACT_STRIDE;
  const int bmask = (fr & 7) << 4;

  float c_state = 0.f;
  int budget = 1 << 22;   // global spin budget: bail to wrong answer, never hang

  // ---- prologue: prefetch x(t=0) into registers (plain load, safe) ----
  u32x4 xcur = {0, 0, 0, 0};
  if (xbf) xcur = *(const u32x4*)xsrc;

  for (int t = 0; t < T_; ++t) {
    u32x4 v0, v1, v2, v3, v4, v5, v6, v7;
    const u32* hb = hbuf + (size_t)(t & 1) * HSLOT + (size_t)(row0 + prow) * H_ + 4 * pw;

#define ISSUE_POLLS()                                                                        \
  do {                                                                                       \
    asm volatile("global_load_dwordx4 %0, %1, off sc0 sc1"             : "=v"(v0) : "v"(hb)); \
    asm volatile("global_load_dwordx4 %0, %1, off offset:256 sc0 sc1"  : "=v"(v1) : "v"(hb)); \
    asm volatile("global_load_dwordx4 %0, %1, off offset:512 sc0 sc1"  : "=v"(v2) : "v"(hb)); \
    asm volatile("global_load_dwordx4 %0, %1, off offset:768 sc0 sc1"  : "=v"(v3) : "v"(hb)); \
    asm volatile("global_load_dwordx4 %0, %1, off offset:1024 sc0 sc1" : "=v"(v4) : "v"(hb)); \
    asm volatile("global_load_dwordx4 %0, %1, off offset:1280 sc0 sc1" : "=v"(v5) : "v"(hb)); \
    asm volatile("global_load_dwordx4 %0, %1, off offset:1536 sc0 sc1" : "=v"(v6) : "v"(hb)); \
    asm volatile("global_load_dwordx4 %0, %1, off offset:1792 sc0 sc1" : "=v"(v7) : "v"(hb)); \
  } while (0)

    if (xbf) {
      // polls first (critical path); x-write is register->LDS, no vmem dep
      ISSUE_POLLS();
      __builtin_amdgcn_sched_barrier(0);
      *(u32x4*)(smem + xw) = xcur;
      if (t + 1 < T_)   // prefetch next x (plain load; compiler-managed wait)
        xcur = *(const u32x4*)(xsrc + (size_t)(t + 1) * 16384);
    } else {
      // fallback: x load first (so its wait doesn't drain the polls: in-order
      // vmcnt retirement means later-consumed earlier-issued is the safe order)
      float4 xv0 = *(const float4*)(xp0 + (size_t)t * F_);
      float4 xv1 = *(const float4*)(xp1 + (size_t)t * F_);
      bf16x4 b0 = { (bf16)xv0.x, (bf16)xv0.y, (bf16)xv0.z, (bf16)xv0.w };
      bf16x4 b1 = { (bf16)xv1.x, (bf16)xv1.y, (bf16)xv1.z, (bf16)xv1.w };
      *(bf16x4*)(smem + xw0) = b0;
      *(bf16x4*)(smem + xw1) = b1;
      ISSUE_POLLS();
      __builtin_amdgcn_sched_barrier(0);
    }

    bar_lds();   // sync1: x region visible; prior step fully consumed.
                 // Polls (and x prefetch) stay IN FLIGHT across this barrier.

    // ---- x-chunk MFMAs (kk 0..3) while the polls land ----
    f32x4 a0 = {0.f, 0.f, 0.f, 0.f}, a1 = {0.f, 0.f, 0.f, 0.f};
    f32x4 a2 = {0.f, 0.f, 0.f, 0.f}, a3 = {0.f, 0.f, 0.f, 0.f};
    {
      bf16x8 p0 = *(const bf16x8*)(bbase + ((0 * 64 + kg * 16) ^ bmask));
      a0 = __builtin_amdgcn_mfma_f32_16x16x32_bf16(wfrag[0], p0, a0, 0, 0, 0);
      bf16x8 p1 = *(const bf16x8*)(bbase + ((1 * 64 + kg * 16) ^ bmask));
      a1 = __builtin_amdgcn_mfma_f32_16x16x32_bf16(wfrag[1], p1, a1, 0, 0, 0);
      bf16x8 p2 = *(const bf16x8*)(bbase + ((2 * 64 + kg * 16) ^ bmask));
      a2 = __builtin_amdgcn_mfma_f32_16x16x32_bf16(wfrag[2], p2, a2, 0, 0, 0);
      bf16x8 p3 = *(const bf16x8*)(bbase + ((3 * 64 + kg * 16) ^ bmask));
      a3 = __builtin_amdgcn_mfma_f32_16x16x32_bf16(wfrag[3], p3, a3, 0, 0, 0);
    }
    __builtin_amdgcn_sched_barrier(0);

    // ---- spin: partial re-poll — reissue only stale vectors ----
    {
      const u32 tgt = (u32)t << 16;
      for (;;) {
        asm volatile("s_waitcnt vmcnt(0)" ::: "memory");
        __builtin_amdgcn_sched_barrier(0);   // rule #18: no hoist of checks
        u32 need = 0;
        if (min4(v0) < tgt) need |= 1u;
        if (min4(v1) < tgt) need |= 2u;
        if (min4(v2) < tgt) need |= 4u;
        if (min4(v3) < tgt) need |= 8u;
        if (min4(v4) < tgt) need |= 16u;
        if (min4(v5) < tgt) need |= 32u;
        if (min4(v6) < tgt) need |= 64u;
        if (min4(v7) < tgt) need |= 128u;
        if (!need) break;
        if (--budget < 0) break;             // bail to wrong-answer, never hang
        if (need & 1u)   asm volatile("global_load_dwordx4 %0, %1, off sc0 sc1"             : "=v"(v0) : "v"(hb));
        if (need & 2u)   asm volatile("global_load_dwordx4 %0, %1, off offset:256 sc0 sc1"  : "=v"(v1) : "v"(hb));
        if (need & 4u)   asm volatile("global_load_dwordx4 %0, %1, off offset:512 sc0 sc1"  : "=v"(v2) : "v"(hb));
        if (need & 8u)   asm volatile("global_load_dwordx4 %0, %1, off offset:768 sc0 sc1"  : "=v"(v3) : "v"(hb));
        if (need & 16u)  asm volatile("global_load_dwordx4 %0, %1, off offset:1024 sc0 sc1" : "=v"(v4) : "v"(hb));
        if (need & 32u)  asm volatile("global_load_dwordx4 %0, %1, off offset:1280 sc0 sc1" : "=v"(v5) : "v"(hb));
        if (need & 64u)  asm volatile("global_load_dwordx4 %0, %1, off offset:1536 sc0 sc1" : "=v"(v6) : "v"(hb));
        if (need & 128u) asm volatile("global_load_dwordx4 %0, %1, off offset:1792 sc0 sc1" : "=v"(v7) : "v"(hb));
      }
    }
#undef ISSUE_POLLS

    // ---- unpack payloads -> act LDS h-region (contiguous 8B per thread) ----
    {
      char* dst = smem + prow * ACT_STRIDE;
      #define UNPACK(i, V)                                                  \
        {                                                                   \
          u32 w0 = (V[0] & 0xffffu) | (V[1] << 16);                         \
          u32 w1 = (V[2] & 0xffffu) | (V[3] << 16);                         \
          u32x2 wp = { w0, w1 };                                            \
          *(u32x2*)(dst + ((256 + 128 * (i) + 8 * pw) ^ swz)) = wp;         \
        }
      UNPACK(0, v0) UNPACK(1, v1) UNPACK(2, v2) UNPACK(3, v3)
      UNPACK(4, v4) UNPACK(5, v5) UNPACK(6, v6) UNPACK(7, v7)
      #undef UNPACK
    }
    bar_lds();   // sync2: h region visible

    // ---- h chunks kk = 4..19 across 4 accumulator chains ----
    #pragma unroll
    for (int kk = 4; kk < 20; kk += 4) {
      bf16x8 b0 = *(const bf16x8*)(bbase + (((kk + 0) * 64 + kg * 16) ^ bmask));
      a0 = __builtin_amdgcn_mfma_f32_16x16x32_bf16(wfrag[kk + 0], b0, a0, 0, 0, 0);
      bf16x8 b1 = *(const bf16x8*)(bbase + (((kk + 1) * 64 + kg * 16) ^ bmask));
      a1 = __builtin_amdgcn_mfma_f32_16x16x32_bf16(wfrag[kk + 1], b1, a1, 0, 0, 0);
      bf16x8 b2 = *(const bf16x8*)(bbase + (((kk + 2) * 64 + kg * 16) ^ bmask));
      a2 = __builtin_amdgcn_mfma_f32_16x16x32_bf16(wfrag[kk + 2], b2, a2, 0, 0, 0);
      bf16x8 b3 = *(const bf16x8*)(bbase + (((kk + 3) * 64 + kg * 16) ^ bmask));
      a3 = __builtin_amdgcn_mfma_f32_16x16x32_bf16(wfrag[kk + 3], b3, a3, 0, 0, 0);
    }
    f32x4 dsum = (a0 + a1) + (a2 + a3);

    // ---- 4x4 transpose across kg groups -> lane holds 4 gate types ----
    float d0 = dsum[0], d1 = dsum[1], d2 = dsum[2], d3 = dsum[3];
    float t0 = __shfl_xor((kg & 2) ? d0 : d2, 32, 64);
    float t1 = __shfl_xor((kg & 2) ? d1 : d3, 32, 64);
    float w0 = (kg & 2) ? t0 : d0;
    float w1 = (kg & 2) ? t1 : d1;
    float w2 = (kg & 2) ? d2 : t0;
    float w3 = (kg & 2) ? d3 : t1;
    float t2 = __shfl_xor((kg & 1) ? w0 : w1, 16, 64);
    float t3 = __shfl_xor((kg & 1) ? w2 : w3, 16, 64);
    float gi = (kg & 1) ? t2 : w0;
    float gf = (kg & 1) ? w1 : t2;
    float gg = (kg & 1) ? t3 : w2;
    float go = (kg & 1) ? w3 : t3;

    // ---- gate math + state update (1 cell per lane) ----
    float iv = sigm(gi + bi_);
    float fv = sigm(gf + bf_);
    float gv = tanh_f(gg + bg_);
    float ov = sigm(go + bo_);
    c_state = fv * c_state + iv * gv;
    float hv = ov * tanh_f(c_state);

    // ---- publish: atomic swap (device-scope, at the coherence point) ----
    u32 val = ((u32)(t + 1) << 16) | bf16bits(hv);
    u32* dstp = hbuf + (size_t)((t + 1) & 1) * HSLOT + (size_t)(row0 + fr) * H_ + jcol;
    asm volatile("global_atomic_swap %0, %1, off" :: "v"(dstp), "v"(val) : "memory");

    if (t == T_ - 1) hf32[(size_t)(row0 + fr) * H_ + jcol] = hv;
  }
}

__global__ void __launch_bounds__(64) out_kernel(
    const float* __restrict__ h_f32,
    const float* __restrict__ Wout,
    const float* __restrict__ bout,
    float* __restrict__ out)
{
  int b = blockIdx.x;
  int lane = threadIdx.x;
  float a0 = 0.f, a1 = 0.f, a2 = 0.f, a3 = 0.f;
  for (int j = lane; j < H_; j += 64) {
    float hv = fmaxf(h_f32[(size_t)b * H_ + j], 0.f);
    a0 += hv * Wout[0 * H_ + j];
    a1 += hv * Wout[1 * H_ + j];
    a2 += hv * Wout[2 * H_ + j];
    a3 += hv * Wout[3 * H_ + j];
  }
  #pragma unroll
  for (int off = 32; off; off >>= 1) {
    a0 += __shfl_down(a0, off);
    a1 += __shfl_down(a1, off);
    a2 += __shfl_down(a2, off);
    a3 += __shfl_down(a3, off);
  }
  if (lane == 0) {
    out[b * 4 + 0] = a0 + bout[0];
    out[b * 4 + 1] = a1 + bout[1];
    out[b * 4 + 2] = a2 + bout[2];
    out[b * 4 + 3] = a3 + bout[3];
  }
}

extern "C" void kernel_launch(void* const* d_in, const int* in_sizes, int n_in,
                              void* d_out, int out_size, void* d_ws, size_t ws_size,
                              hipStream_t stream) {
  const float* x    = (const float*)d_in[0];
  const float* Wih  = (const float*)d_in[1];
  const float* Whh  = (const float*)d_in[2];
  const float* bih  = (const float*)d_in[3];
  const float* bhh  = (const float*)d_in[4];
  // d_in[5..8] = layer-1 weights: dead code in the reference, unused.
  const float* Wout = (const float*)d_in[9];
  const float* bout = (const float*)d_in[10];

  char* ws = (char*)d_ws;
  u32*   hbuf = (u32*)ws;                    // 262144 B
  float* hf32 = (float*)(ws + 262144);       // 131072 B
  const size_t XBF_OFF = 393216;
  const size_t XBF_SZ = (size_t)T_ * 4 * 16 * 128 * 2;   // 33554432 B
  bf16* xbf = (ws_size >= XBF_OFF + XBF_SZ) ? (bf16*)(ws + XBF_OFF) : nullptr;

  hipLaunchKernelGGL(prep_kernel, dim3(256), dim3(NTHR), 0, stream, hbuf);
  if (xbf)
    hipLaunchKernelGGL(xconv_kernel, dim3(64, 8), dim3(NTHR), 0, stream, x, xbf);

  void* args[] = { (void*)&x, (void*)&Wih, (void*)&Whh, (void*)&bih, (void*)&bhh,
                   (void*)&hbuf, (void*)&hf32, (void*)&xbf };
  hipLaunchCooperativeKernel((void*)lstm_kernel, dim3(NBLK), dim3(NTHR),
                             args, 0, stream);

  hipLaunchKernelGGL(out_kernel, dim3(B_), dim3(64), 0, stream,
                     hf32, Wout, bout, (float*)d_out);
}

// Round 15
// 4281.422 us; speedup vs baseline: 1.6416x; 1.6416x over previous
//
#include <hip/hip_runtime.h>
#include <hip/hip_bf16.h>
#include <cstdint>
#include <cstddef>

// LSTM_3624952398014 — R15: R8 + the two isolated wins from R14's bundle.
//  * sync1 is an LDS-only barrier (lgkmcnt(0)+s_barrier): __syncthreads was
//    draining vmcnt(0) = our OWN atomic publish (~500cy) + x load, pure
//    self-waiting (visibility to peers happens at the LLC regardless).
//  * x prefetched to a register one step ahead (plain load issued AFTER
//    sync1 beside the polls; spin's vmcnt(0) retires it under the poll RT).
//  * Polls stay in R8's position (after sync1, hidden by x-MFMAs) — R14
//    proved early polls are stale polls (FETCH 1.19->1.70GB, more rounds).
// Everything else byte-identical to R8 (best, 3.92ms): tag16|bf16 words,
// global_atomic_swap publish, sc0sc1 polls, min-tree + partial re-poll,
// spin budget, rcp gate math, 128blk x 256thr, 1 tile/wave, W in 80 VGPRs.
// Layer 1 of the reference is dead code; out = relu(h_final(L0)) @ W_out^T + b.

#define B_ 64
#define T_ 2048
#define F_ 128
#define H_ 512

#define NBLK 128
#define NTHR 256

#define ACT_STRIDE 1280                 // 640 bf16 per act row
#define SMEM_SZ (16 * ACT_STRIDE)       // 20480 B
#define HSLOT (B_ * H_)                 // 32768 tagged u32 per slot

typedef __bf16 bf16;
typedef __bf16 bf16x4 __attribute__((ext_vector_type(4)));
typedef __bf16 bf16x8 __attribute__((ext_vector_type(8)));
typedef float f32x4 __attribute__((ext_vector_type(4)));
typedef unsigned int u32;
typedef u32 u32x2 __attribute__((ext_vector_type(2)));
typedef u32 u32x4 __attribute__((ext_vector_type(4)));

static __device__ __forceinline__ float sigm(float v) {
  return __builtin_amdgcn_rcpf(1.f + __expf(-v));
}
static __device__ __forceinline__ float tanh_f(float v) {
  float a = fminf(fabsf(v), 20.f);
  float e = __expf(-2.f * a);
  float t = 1.f - 2.f * e * __builtin_amdgcn_rcpf(1.f + e);
  return copysignf(t, v);
}
static __device__ __forceinline__ u32 bf16bits(float f) {
  bf16 b = (bf16)f;
  unsigned short us;
  __builtin_memcpy(&us, &b, 2);
  return (u32)us;
}
static __device__ __forceinline__ u32 min4(u32x4 v) {
  u32 a = v[0] < v[1] ? v[0] : v[1];
  u32 b = v[2] < v[3] ? v[2] : v[3];
  return a < b ? a : b;
}
// LDS-only barrier: waits LDS ops, does NOT drain VMEM (unlike __syncthreads).
static __device__ __forceinline__ void bar_lds() {
  asm volatile("s_waitcnt lgkmcnt(0)" ::: "memory");
  __builtin_amdgcn_s_barrier();
  __builtin_amdgcn_sched_barrier(0);
}

__global__ void __launch_bounds__(NTHR) prep_kernel(u32* hbuf) {
  int idx = blockIdx.x * blockDim.x + threadIdx.x;   // 256*256 = 65536 = 2*HSLOT
  if (idx < 2 * HSLOT) hbuf[idx] = 0u;               // both slots: tag 0, h = 0
}

// x [B][T][F] f32  ->  xbf [T][4 rg][16 row][128] bf16
__global__ void __launch_bounds__(NTHR) xconv_kernel(
    const float* __restrict__ x, bf16* __restrict__ xbf) {
  const int b = blockIdx.x;          // 0..63
  const int t0 = blockIdx.y * 256;   // grid.y = 8
  const int f2 = threadIdx.x & 63;   // 2 floats per thread
  const int tq = threadIdx.x >> 6;   // 0..3
  const int rg = b >> 4, row = b & 15;
  for (int i = 0; i < 64; ++i) {
    int t = t0 + i * 4 + tq;
    float2 xv = *(const float2*)(x + ((size_t)b * T_ + t) * F_ + 2 * f2);
    u32 w = bf16bits(xv.x) | (bf16bits(xv.y) << 16);
    *(u32*)((char*)xbf + ((((size_t)t * 4 + rg) * 16 + row) * 128 + 2 * f2) * 2) = w;
  }
}

__global__ void __launch_bounds__(NTHR, 1) lstm_kernel(
    const float* __restrict__ x,
    const float* __restrict__ Wih,
    const float* __restrict__ Whh,
    const float* __restrict__ bih,
    const float* __restrict__ bhh,
    u32* __restrict__ hbuf,        // [2][B_][H_] tagged u32
    float* __restrict__ hf32,      // [B_][H_] final h fp32
    const bf16* __restrict__ xbf)  // [T][4][16][128] bf16 or nullptr
{
  __shared__ __align__(16) char smem[SMEM_SZ];

  const int tid = threadIdx.x;
  const int bid = blockIdx.x;
  const int rg = bid >> 5;          // 0..3
  const int jg = bid & 31;          // 0..31
  const int row0 = rg * 16;
  const int j0 = jg * 16;

  const int lane = tid & 63;
  const int wave = tid >> 6;        // 0..3
  const int fr = lane & 15;
  const int kg = lane >> 4;         // 0..3

  // ---- one-time: W slice -> register A-fragments (1 tile/wave, 80 VGPR) ----
  bf16x8 wfrag[20];
  {
    const int G = (fr >> 2) * H_ + j0 + wave * 4 + (fr & 3);
    const float* sih = Wih + (size_t)G * F_;
    const float* shh = Whh + (size_t)G * H_;
    #pragma unroll
    for (int kk = 0; kk < 20; ++kk) {
      const float* s = (kk < 4) ? (sih + kk * 32 + kg * 8)
                                : (shh + (kk - 4) * 32 + kg * 8);
      float4 f0 = *(const float4*)s;
      float4 f1 = *(const float4*)(s + 4);
      bf16x8 w = { (bf16)f0.x, (bf16)f0.y, (bf16)f0.z, (bf16)f0.w,
                   (bf16)f1.x, (bf16)f1.y, (bf16)f1.z, (bf16)f1.w };
      wfrag[kk] = w;
    }
  }

  // per-lane cell (post-transpose): b = row0+fr, j = j0 + wave*4 + kg
  const int jcol = j0 + wave * 4 + kg;
  const float bi_ = bih[0 * H_ + jcol] + bhh[0 * H_ + jcol];
  const float bf_ = bih[1 * H_ + jcol] + bhh[1 * H_ + jcol];
  const float bg_ = bih[2 * H_ + jcol] + bhh[2 * H_ + jcol];
  const float bo_ = bih[3 * H_ + jcol] + bhh[3 * H_ + jcol];

  // poll/unpack ids
  const int prow = tid >> 4;        // 0..15
  const int pw = tid & 15;
  // f32-fallback x staging ids
  const int r0x = tid >> 5;
  const int c40 = tid & 31;
  const float* xp0 = x + (size_t)(row0 + r0x) * T_ * F_ + c40 * 4;
  const float* xp1 = x + (size_t)(row0 + r0x + 8) * T_ * F_ + c40 * 4;
  const int xw0 = r0x * ACT_STRIDE + ((8 * c40) ^ ((r0x & 7) << 4));
  const int xw1 = (r0x + 8) * ACT_STRIDE + ((8 * c40) ^ (((r0x + 8) & 7) << 4));
  // bf16 x staging ids (row = tid>>4, 16B seg = tid&15)
  const int xw = prow * ACT_STRIDE + ((pw * 16) ^ ((prow & 7) << 4));
  const char* xsrc = (const char*)xbf + (size_t)rg * 4096 + tid * 16;

  const char* bbase = smem + fr * ACT_STRIDE;
  const int bmask = (fr & 7) << 4;

  float c_state = 0.f;
  int budget = 1 << 22;   // global spin budget: bail to wrong answer, never hang

  // ---- prologue: prefetch x(t=0) into a register (plain load, safe) ----
  u32x4 xcur = {0, 0, 0, 0};
  if (xbf) xcur = *(const u32x4*)xsrc;

  for (int t = 0; t < T_; ++t) {
    // ---- stage x_t into LDS x-region (register -> LDS on the xbf path) ----
    if (xbf) {
      *(u32x4*)(smem + xw) = xcur;
      bar_lds();   // sync1: LDS-only. Does NOT wait for our own atomic publish
                   // or any VMEM — that wait was pure self-inflicted serial cost.
    } else {
      float4 xv0 = *(const float4*)(xp0 + (size_t)t * F_);
      float4 xv1 = *(const float4*)(xp1 + (size_t)t * F_);
      bf16x4 b0 = { (bf16)xv0.x, (bf16)xv0.y, (bf16)xv0.z, (bf16)xv0.w };
      bf16x4 b1 = { (bf16)xv1.x, (bf16)xv1.y, (bf16)xv1.z, (bf16)xv1.w };
      *(bf16x4*)(smem + xw0) = b0;
      *(bf16x4*)(smem + xw1) = b1;
      __syncthreads();   // fallback keeps the conservative barrier
    }

    // ---- issue poll loads (R8 position); x-MFMAs hide the first RT ----
    u32x4 v0, v1, v2, v3, v4, v5, v6, v7;
    const u32* hb = hbuf + (size_t)(t & 1) * HSLOT + (size_t)(row0 + prow) * H_ + 4 * pw;
    asm volatile("global_load_dwordx4 %0, %1, off sc0 sc1"              : "=v"(v0) : "v"(hb));
    asm volatile("global_load_dwordx4 %0, %1, off offset:256 sc0 sc1"   : "=v"(v1) : "v"(hb));
    asm volatile("global_load_dwordx4 %0, %1, off offset:512 sc0 sc1"   : "=v"(v2) : "v"(hb));
    asm volatile("global_load_dwordx4 %0, %1, off offset:768 sc0 sc1"   : "=v"(v3) : "v"(hb));
    asm volatile("global_load_dwordx4 %0, %1, off offset:1024 sc0 sc1"  : "=v"(v4) : "v"(hb));
    asm volatile("global_load_dwordx4 %0, %1, off offset:1280 sc0 sc1"  : "=v"(v5) : "v"(hb));
    asm volatile("global_load_dwordx4 %0, %1, off offset:1536 sc0 sc1"  : "=v"(v6) : "v"(hb));
    asm volatile("global_load_dwordx4 %0, %1, off offset:1792 sc0 sc1"  : "=v"(v7) : "v"(hb));
    __builtin_amdgcn_sched_barrier(0);

    // prefetch next step's x (plain load; retires under the poll RT)
    if (xbf && t + 1 < T_)
      xcur = *(const u32x4*)(xsrc + (size_t)(t + 1) * 16384);

    f32x4 a0 = {0.f, 0.f, 0.f, 0.f}, a1 = {0.f, 0.f, 0.f, 0.f};
    f32x4 a2 = {0.f, 0.f, 0.f, 0.f}, a3 = {0.f, 0.f, 0.f, 0.f};
    {
      bf16x8 p0 = *(const bf16x8*)(bbase + ((0 * 64 + kg * 16) ^ bmask));
      a0 = __builtin_amdgcn_mfma_f32_16x16x32_bf16(wfrag[0], p0, a0, 0, 0, 0);
      bf16x8 p1 = *(const bf16x8*)(bbase + ((1 * 64 + kg * 16) ^ bmask));
      a1 = __builtin_amdgcn_mfma_f32_16x16x32_bf16(wfrag[1], p1, a1, 0, 0, 0);
      bf16x8 p2 = *(const bf16x8*)(bbase + ((2 * 64 + kg * 16) ^ bmask));
      a2 = __builtin_amdgcn_mfma_f32_16x16x32_bf16(wfrag[2], p2, a2, 0, 0, 0);
      bf16x8 p3 = *(const bf16x8*)(bbase + ((3 * 64 + kg * 16) ^ bmask));
      a3 = __builtin_amdgcn_mfma_f32_16x16x32_bf16(wfrag[3], p3, a3, 0, 0, 0);
    }
    __builtin_amdgcn_sched_barrier(0);

    // ---- spin: partial re-poll — reissue only stale vectors ----
    {
      const u32 tgt = (u32)t << 16;
      for (;;) {
        asm volatile("s_waitcnt vmcnt(0)" ::: "memory");
        __builtin_amdgcn_sched_barrier(0);   // rule #18: no hoist of checks
        u32 need = 0;
        if (min4(v0) < tgt) need |= 1u;
        if (min4(v1) < tgt) need |= 2u;
        if (min4(v2) < tgt) need |= 4u;
        if (min4(v3) < tgt) need |= 8u;
        if (min4(v4) < tgt) need |= 16u;
        if (min4(v5) < tgt) need |= 32u;
        if (min4(v6) < tgt) need |= 64u;
        if (min4(v7) < tgt) need |= 128u;
        if (!need) break;
        if (--budget < 0) break;             // bail to wrong-answer, never hang
        if (need & 1u)   asm volatile("global_load_dwordx4 %0, %1, off sc0 sc1"             : "=v"(v0) : "v"(hb));
        if (need & 2u)   asm volatile("global_load_dwordx4 %0, %1, off offset:256 sc0 sc1"  : "=v"(v1) : "v"(hb));
        if (need & 4u)   asm volatile("global_load_dwordx4 %0, %1, off offset:512 sc0 sc1"  : "=v"(v2) : "v"(hb));
        if (need & 8u)   asm volatile("global_load_dwordx4 %0, %1, off offset:768 sc0 sc1"  : "=v"(v3) : "v"(hb));
        if (need & 16u)  asm volatile("global_load_dwordx4 %0, %1, off offset:1024 sc0 sc1" : "=v"(v4) : "v"(hb));
        if (need & 32u)  asm volatile("global_load_dwordx4 %0, %1, off offset:1280 sc0 sc1" : "=v"(v5) : "v"(hb));
        if (need & 64u)  asm volatile("global_load_dwordx4 %0, %1, off offset:1536 sc0 sc1" : "=v"(v6) : "v"(hb));
        if (need & 128u) asm volatile("global_load_dwordx4 %0, %1, off offset:1792 sc0 sc1" : "=v"(v7) : "v"(hb));
      }
    }

    // ---- unpack payloads -> act LDS h-region (contiguous 8B per thread) ----
    {
      char* dst = smem + prow * ACT_STRIDE;
      const int swz = (prow & 7) << 4;
      #define UNPACK(i, V)                                                  \
        {                                                                   \
          u32 w0 = (V[0] & 0xffffu) | (V[1] << 16);                         \
          u32 w1 = (V[2] & 0xffffu) | (V[3] << 16);                         \
          u32x2 wp = { w0, w1 };                                            \
          *(u32x2*)(dst + ((256 + 128 * (i) + 8 * pw) ^ swz)) = wp;         \
        }
      UNPACK(0, v0) UNPACK(1, v1) UNPACK(2, v2) UNPACK(3, v3)
      UNPACK(4, v4) UNPACK(5, v5) UNPACK(6, v6) UNPACK(7, v7)
      #undef UNPACK
    }
    bar_lds();   // sync2: h region visible (LDS-only is sufficient here too)

    // ---- h chunks kk = 4..19 across 4 accumulator chains ----
    #pragma unroll
    for (int kk = 4; kk < 20; kk += 4) {
      bf16x8 b0 = *(const bf16x8*)(bbase + (((kk + 0) * 64 + kg * 16) ^ bmask));
      a0 = __builtin_amdgcn_mfma_f32_16x16x32_bf16(wfrag[kk + 0], b0, a0, 0, 0, 0);
      bf16x8 b1 = *(const bf16x8*)(bbase + (((kk + 1) * 64 + kg * 16) ^ bmask));
      a1 = __builtin_amdgcn_mfma_f32_16x16x32_bf16(wfrag[kk + 1], b1, a1, 0, 0, 0);
      bf16x8 b2 = *(const bf16x8*)(bbase + (((kk + 2) * 64 + kg * 16) ^ bmask));
      a2 = __builtin_amdgcn_mfma_f32_16x16x32_bf16(wfrag[kk + 2], b2, a2, 0, 0, 0);
      bf16x8 b3 = *(const bf16x8*)(bbase + (((kk + 3) * 64 + kg * 16) ^ bmask));
      a3 = __builtin_amdgcn_mfma_f32_16x16x32_bf16(wfrag[kk + 3], b3, a3, 0, 0, 0);
    }
    f32x4 dsum = (a0 + a1) + (a2 + a3);

    // ---- 4x4 transpose across kg groups -> lane holds 4 gate types ----
    float d0 = dsum[0], d1 = dsum[1], d2 = dsum[2], d3 = dsum[3];
    float t0 = __shfl_xor((kg & 2) ? d0 : d2, 32, 64);
    float t1 = __shfl_xor((kg & 2) ? d1 : d3, 32, 64);
    float w0 = (kg & 2) ? t0 : d0;
    float w1 = (kg & 2) ? t1 : d1;
    float w2 = (kg & 2) ? d2 : t0;
    float w3 = (kg & 2) ? d3 : t1;
    float t2 = __shfl_xor((kg & 1) ? w0 : w1, 16, 64);
    float t3 = __shfl_xor((kg & 1) ? w2 : w3, 16, 64);
    float gi = (kg & 1) ? t2 : w0;
    float gf = (kg & 1) ? w1 : t2;
    float gg = (kg & 1) ? t3 : w2;
    float go = (kg & 1) ? w3 : t3;

    // ---- gate math + state update (1 cell per lane) ----
    float iv = sigm(gi + bi_);
    float fv = sigm(gf + bf_);
    float gv = tanh_f(gg + bg_);
    float ov = sigm(go + bo_);
    c_state = fv * c_state + iv * gv;
    float hv = ov * tanh_f(c_state);

    // ---- publish: atomic swap (device-scope, at the coherence point) ----
    u32 val = ((u32)(t + 1) << 16) | bf16bits(hv);
    u32* dstp = hbuf + (size_t)((t + 1) & 1) * HSLOT + (size_t)(row0 + fr) * H_ + jcol;
    asm volatile("global_atomic_swap %0, %1, off" :: "v"(dstp), "v"(val) : "memory");

    if (t == T_ - 1) hf32[(size_t)(row0 + fr) * H_ + jcol] = hv;
  }
}

__global__ void __launch_bounds__(64) out_kernel(
    const float* __restrict__ h_f32,
    const float* __restrict__ Wout,
    const float* __restrict__ bout,
    float* __restrict__ out)
{
  int b = blockIdx.x;
  int lane = threadIdx.x;
  float a0 = 0.f, a1 = 0.f, a2 = 0.f, a3 = 0.f;
  for (int j = lane; j < H_; j += 64) {
    float hv = fmaxf(h_f32[(size_t)b * H_ + j], 0.f);
    a0 += hv * Wout[0 * H_ + j];
    a1 += hv * Wout[1 * H_ + j];
    a2 += hv * Wout[2 * H_ + j];
    a3 += hv * Wout[3 * H_ + j];
  }
  #pragma unroll
  for (int off = 32; off; off >>= 1) {
    a0 += __shfl_down(a0, off);
    a1 += __shfl_down(a1, off);
    a2 += __shfl_down(a2, off);
    a3 += __shfl_down(a3, off);
  }
  if (lane == 0) {
    out[b * 4 + 0] = a0 + bout[0];
    out[b * 4 + 1] = a1 + bout[1];
    out[b * 4 + 2] = a2 + bout[2];
    out[b * 4 + 3] = a3 + bout[3];
  }
}

extern "C" void kernel_launch(void* const* d_in, const int* in_sizes, int n_in,
                              void* d_out, int out_size, void* d_ws, size_t ws_size,
                              hipStream_t stream) {
  const float* x    = (const float*)d_in[0];
  const float* Wih  = (const float*)d_in[1];
  const float* Whh  = (const float*)d_in[2];
  const float* bih  = (const float*)d_in[3];
  const float* bhh  = (const float*)d_in[4];
  // d_in[5..8] = layer-1 weights: dead code in the reference, unused.
  const float* Wout = (const float*)d_in[9];
  const float* bout = (const float*)d_in[10];

  char* ws = (char*)d_ws;
  u32*   hbuf = (u32*)ws;                    // 262144 B
  float* hf32 = (float*)(ws + 262144);       // 131072 B
  const size_t XBF_OFF = 393216;
  const size_t XBF_SZ = (size_t)T_ * 4 * 16 * 128 * 2;   // 33554432 B
  bf16* xbf = (ws_size >= XBF_OFF + XBF_SZ) ? (bf16*)(ws + XBF_OFF) : nullptr;

  hipLaunchKernelGGL(prep_kernel, dim3(256), dim3(NTHR), 0, stream, hbuf);
  if (xbf)
    hipLaunchKernelGGL(xconv_kernel, dim3(64, 8), dim3(NTHR), 0, stream, x, xbf);

  void* args[] = { (void*)&x, (void*)&Wih, (void*)&Whh, (void*)&bih, (void*)&bhh,
                   (void*)&hbuf, (void*)&hf32, (void*)&xbf };
  hipLaunchCooperativeKernel((void*)lstm_kernel, dim3(NBLK), dim3(NTHR),
                             args, 0, stream);

  hipLaunchKernelGGL(out_kernel, dim3(B_), dim3(64), 0, stream,
                     hf32, Wout, bout, (float*)d_out);
}

// Round 16
// 4133.759 us; speedup vs baseline: 1.7002x; 1.0357x over previous
//
#include <hip/hip_runtime.h>
#include <hip/hip_bf16.h>
#include <cstdint>
#include <cstddef>

// LSTM_3624952398014 — R16: R8 (best, 3.92ms) + ONE change: coalesced publish.
// R8 published 32768 scattered 4B atomic-swaps/step (RMW, serialized per
// address at the coherence point; consumer's tag-check waits for the LAST
// word). R16: lane writes its tagged word to an LDS pub tile (16B-aligned
// rows, 2-way-conflict free); same-wave lgkmcnt(0); kg==0 lanes store one
// dwordx4 per row (4 j-words) -> 8192 plain write-through stores, 4x fewer
// messages, no RMW. Everything else byte-identical to R8: poll position
// (after sync1, hidden under x-MFMAs — R14 proved earlier is worse),
// __syncthreads barriers (R15 proved LDS-only is worse), tag16|bf16 words,
// min-tree + partial re-poll, spin budget, rcp gate math, 128blk x 256thr,
// 1 MFMA tile/wave, W in 80 VGPRs.
// If this is flat: residual = store->LLC->poll RT + 128-block skew = the
// practical floor of this algorithm class (latency-, not roofline-bound).
// Layer 1 of the reference is dead code; out = relu(h_final(L0)) @ W_out^T + b.

#define B_ 64
#define T_ 2048
#define F_ 128
#define H_ 512

#define NBLK 128
#define NTHR 256

#define ACT_STRIDE 1280                 // 640 bf16 per act row
#define PUB_BASE (16 * ACT_STRIDE)      // 20480
#define PUB_ROW 80                      // 16 words + 16B pad; 16B-aligned rows
#define SMEM_SZ (PUB_BASE + 16 * PUB_ROW)   // 21760 B
#define HSLOT (B_ * H_)                 // 32768 tagged u32 per slot

typedef __bf16 bf16;
typedef __bf16 bf16x4 __attribute__((ext_vector_type(4)));
typedef __bf16 bf16x8 __attribute__((ext_vector_type(8)));
typedef float f32x4 __attribute__((ext_vector_type(4)));
typedef unsigned int u32;
typedef u32 u32x2 __attribute__((ext_vector_type(2)));
typedef u32 u32x4 __attribute__((ext_vector_type(4)));

static __device__ __forceinline__ float sigm(float v) {
  return __builtin_amdgcn_rcpf(1.f + __expf(-v));
}
static __device__ __forceinline__ float tanh_f(float v) {
  float a = fminf(fabsf(v), 20.f);
  float e = __expf(-2.f * a);
  float t = 1.f - 2.f * e * __builtin_amdgcn_rcpf(1.f + e);
  return copysignf(t, v);
}
static __device__ __forceinline__ u32 bf16bits(float f) {
  bf16 b = (bf16)f;
  unsigned short us;
  __builtin_memcpy(&us, &b, 2);
  return (u32)us;
}
static __device__ __forceinline__ u32 min4(u32x4 v) {
  u32 a = v[0] < v[1] ? v[0] : v[1];
  u32 b = v[2] < v[3] ? v[2] : v[3];
  return a < b ? a : b;
}

__global__ void __launch_bounds__(NTHR) prep_kernel(u32* hbuf) {
  int idx = blockIdx.x * blockDim.x + threadIdx.x;   // 256*256 = 65536 = 2*HSLOT
  if (idx < 2 * HSLOT) hbuf[idx] = 0u;               // both slots: tag 0, h = 0
}

// x [B][T][F] f32  ->  xbf [T][4 rg][16 row][128] bf16
__global__ void __launch_bounds__(NTHR) xconv_kernel(
    const float* __restrict__ x, bf16* __restrict__ xbf) {
  const int b = blockIdx.x;          // 0..63
  const int t0 = blockIdx.y * 256;   // grid.y = 8
  const int f2 = threadIdx.x & 63;   // 2 floats per thread
  const int tq = threadIdx.x >> 6;   // 0..3
  const int rg = b >> 4, row = b & 15;
  for (int i = 0; i < 64; ++i) {
    int t = t0 + i * 4 + tq;
    float2 xv = *(const float2*)(x + ((size_t)b * T_ + t) * F_ + 2 * f2);
    u32 w = bf16bits(xv.x) | (bf16bits(xv.y) << 16);
    *(u32*)((char*)xbf + ((((size_t)t * 4 + rg) * 16 + row) * 128 + 2 * f2) * 2) = w;
  }
}

__global__ void __launch_bounds__(NTHR, 1) lstm_kernel(
    const float* __restrict__ x,
    const float* __restrict__ Wih,
    const float* __restrict__ Whh,
    const float* __restrict__ bih,
    const float* __restrict__ bhh,
    u32* __restrict__ hbuf,        // [2][B_][H_] tagged u32
    float* __restrict__ hf32,      // [B_][H_] final h fp32
    const bf16* __restrict__ xbf)  // [T][4][16][128] bf16 or nullptr
{
  __shared__ __align__(16) char smem[SMEM_SZ];

  const int tid = threadIdx.x;
  const int bid = blockIdx.x;
  const int rg = bid >> 5;          // 0..3
  const int jg = bid & 31;          // 0..31
  const int row0 = rg * 16;
  const int j0 = jg * 16;

  const int lane = tid & 63;
  const int wave = tid >> 6;        // 0..3
  const int fr = lane & 15;
  const int kg = lane >> 4;         // 0..3

  // ---- one-time: W slice -> register A-fragments (1 tile/wave, 80 VGPR) ----
  bf16x8 wfrag[20];
  {
    const int G = (fr >> 2) * H_ + j0 + wave * 4 + (fr & 3);
    const float* sih = Wih + (size_t)G * F_;
    const float* shh = Whh + (size_t)G * H_;
    #pragma unroll
    for (int kk = 0; kk < 20; ++kk) {
      const float* s = (kk < 4) ? (sih + kk * 32 + kg * 8)
                                : (shh + (kk - 4) * 32 + kg * 8);
      float4 f0 = *(const float4*)s;
      float4 f1 = *(const float4*)(s + 4);
      bf16x8 w = { (bf16)f0.x, (bf16)f0.y, (bf16)f0.z, (bf16)f0.w,
                   (bf16)f1.x, (bf16)f1.y, (bf16)f1.z, (bf16)f1.w };
      wfrag[kk] = w;
    }
  }

  // per-lane cell (post-transpose): b = row0+fr, j = j0 + wave*4 + kg
  const int jcol = j0 + wave * 4 + kg;
  const float bi_ = bih[0 * H_ + jcol] + bhh[0 * H_ + jcol];
  const float bf_ = bih[1 * H_ + jcol] + bhh[1 * H_ + jcol];
  const float bg_ = bih[2 * H_ + jcol] + bhh[2 * H_ + jcol];
  const float bo_ = bih[3 * H_ + jcol] + bhh[3 * H_ + jcol];

  // poll/unpack ids
  const int prow = tid >> 4;        // 0..15
  const int pw = tid & 15;
  // f32-fallback x staging ids
  const int r0x = tid >> 5;
  const int c40 = tid & 31;
  const float* xp0 = x + (size_t)(row0 + r0x) * T_ * F_ + c40 * 4;
  const float* xp1 = x + (size_t)(row0 + r0x + 8) * T_ * F_ + c40 * 4;
  const int xw0 = r0x * ACT_STRIDE + ((8 * c40) ^ ((r0x & 7) << 4));
  const int xw1 = (r0x + 8) * ACT_STRIDE + ((8 * c40) ^ (((r0x + 8) & 7) << 4));
  // bf16 x staging ids (row = tid>>4, 16B seg = tid&15)
  const int xw = prow * ACT_STRIDE + ((pw * 16) ^ ((prow & 7) << 4));

  const char* bbase = smem + fr * ACT_STRIDE;
  const int bmask = (fr & 7) << 4;

  // pub tile addresses (16B-aligned rows; 2-way bank aliasing only = free)
  char* pub_w = smem + PUB_BASE + fr * PUB_ROW + (wave * 4 + kg) * 4;
  const char* pub_r = smem + PUB_BASE + fr * PUB_ROW + wave * 16;

  float c_state = 0.f;
  int budget = 1 << 22;   // global spin budget: bail to wrong answer, never hang

  for (int t = 0; t < T_; ++t) {
    // ---- stage x_t into LDS x-region [0,256)B per row ----
    if (xbf) {
      u32x4 xv = *(const u32x4*)((const char*)xbf
                  + ((size_t)t * 4 + rg) * 4096 + tid * 16);
      *(u32x4*)(smem + xw) = xv;
    } else {
      float4 xv0 = *(const float4*)(xp0 + (size_t)t * F_);
      float4 xv1 = *(const float4*)(xp1 + (size_t)t * F_);
      bf16x4 b0 = { (bf16)xv0.x, (bf16)xv0.y, (bf16)xv0.z, (bf16)xv0.w };
      bf16x4 b1 = { (bf16)xv1.x, (bf16)xv1.y, (bf16)xv1.z, (bf16)xv1.w };
      *(bf16x4*)(smem + xw0) = b0;
      *(bf16x4*)(smem + xw1) = b1;
    }
    __syncthreads();   // sync1: x ready; prior step fully consumed

    // ---- issue poll loads; x-chunk MFMAs hide the first round trip ----
    u32x4 v0, v1, v2, v3, v4, v5, v6, v7;
    const u32* hb = hbuf + (size_t)(t & 1) * HSLOT + (size_t)(row0 + prow) * H_ + 4 * pw;
    asm volatile("global_load_dwordx4 %0, %1, off sc0 sc1"              : "=v"(v0) : "v"(hb));
    asm volatile("global_load_dwordx4 %0, %1, off offset:256 sc0 sc1"   : "=v"(v1) : "v"(hb));
    asm volatile("global_load_dwordx4 %0, %1, off offset:512 sc0 sc1"   : "=v"(v2) : "v"(hb));
    asm volatile("global_load_dwordx4 %0, %1, off offset:768 sc0 sc1"   : "=v"(v3) : "v"(hb));
    asm volatile("global_load_dwordx4 %0, %1, off offset:1024 sc0 sc1"  : "=v"(v4) : "v"(hb));
    asm volatile("global_load_dwordx4 %0, %1, off offset:1280 sc0 sc1"  : "=v"(v5) : "v"(hb));
    asm volatile("global_load_dwordx4 %0, %1, off offset:1536 sc0 sc1"  : "=v"(v6) : "v"(hb));
    asm volatile("global_load_dwordx4 %0, %1, off offset:1792 sc0 sc1"  : "=v"(v7) : "v"(hb));
    __builtin_amdgcn_sched_barrier(0);

    f32x4 a0 = {0.f, 0.f, 0.f, 0.f}, a1 = {0.f, 0.f, 0.f, 0.f};
    f32x4 a2 = {0.f, 0.f, 0.f, 0.f}, a3 = {0.f, 0.f, 0.f, 0.f};
    {
      bf16x8 p0 = *(const bf16x8*)(bbase + ((0 * 64 + kg * 16) ^ bmask));
      a0 = __builtin_amdgcn_mfma_f32_16x16x32_bf16(wfrag[0], p0, a0, 0, 0, 0);
      bf16x8 p1 = *(const bf16x8*)(bbase + ((1 * 64 + kg * 16) ^ bmask));
      a1 = __builtin_amdgcn_mfma_f32_16x16x32_bf16(wfrag[1], p1, a1, 0, 0, 0);
      bf16x8 p2 = *(const bf16x8*)(bbase + ((2 * 64 + kg * 16) ^ bmask));
      a2 = __builtin_amdgcn_mfma_f32_16x16x32_bf16(wfrag[2], p2, a2, 0, 0, 0);
      bf16x8 p3 = *(const bf16x8*)(bbase + ((3 * 64 + kg * 16) ^ bmask));
      a3 = __builtin_amdgcn_mfma_f32_16x16x32_bf16(wfrag[3], p3, a3, 0, 0, 0);
    }
    __builtin_amdgcn_sched_barrier(0);

    // ---- spin: partial re-poll — reissue only stale vectors ----
    {
      const u32 tgt = (u32)t << 16;
      for (;;) {
        asm volatile("s_waitcnt vmcnt(0)" ::: "memory");
        __builtin_amdgcn_sched_barrier(0);   // rule #18: no hoist of checks
        u32 need = 0;
        if (min4(v0) < tgt) need |= 1u;
        if (min4(v1) < tgt) need |= 2u;
        if (min4(v2) < tgt) need |= 4u;
        if (min4(v3) < tgt) need |= 8u;
        if (min4(v4) < tgt) need |= 16u;
        if (min4(v5) < tgt) need |= 32u;
        if (min4(v6) < tgt) need |= 64u;
        if (min4(v7) < tgt) need |= 128u;
        if (!need) break;
        if (--budget < 0) break;             // bail to wrong-answer, never hang
        if (need & 1u)   asm volatile("global_load_dwordx4 %0, %1, off sc0 sc1"             : "=v"(v0) : "v"(hb));
        if (need & 2u)   asm volatile("global_load_dwordx4 %0, %1, off offset:256 sc0 sc1"  : "=v"(v1) : "v"(hb));
        if (need & 4u)   asm volatile("global_load_dwordx4 %0, %1, off offset:512 sc0 sc1"  : "=v"(v2) : "v"(hb));
        if (need & 8u)   asm volatile("global_load_dwordx4 %0, %1, off offset:768 sc0 sc1"  : "=v"(v3) : "v"(hb));
        if (need & 16u)  asm volatile("global_load_dwordx4 %0, %1, off offset:1024 sc0 sc1" : "=v"(v4) : "v"(hb));
        if (need & 32u)  asm volatile("global_load_dwordx4 %0, %1, off offset:1280 sc0 sc1" : "=v"(v5) : "v"(hb));
        if (need & 64u)  asm volatile("global_load_dwordx4 %0, %1, off offset:1536 sc0 sc1" : "=v"(v6) : "v"(hb));
        if (need & 128u) asm volatile("global_load_dwordx4 %0, %1, off offset:1792 sc0 sc1" : "=v"(v7) : "v"(hb));
      }
    }

    // ---- unpack payloads -> act LDS h-region (contiguous 8B per thread) ----
    {
      char* dst = smem + prow * ACT_STRIDE;
      const int swz = (prow & 7) << 4;
      #define UNPACK(i, V)                                                  \
        {                                                                   \
          u32 w0 = (V[0] & 0xffffu) | (V[1] << 16);                         \
          u32 w1 = (V[2] & 0xffffu) | (V[3] << 16);                         \
          u32x2 wp = { w0, w1 };                                            \
          *(u32x2*)(dst + ((256 + 128 * (i) + 8 * pw) ^ swz)) = wp;         \
        }
      UNPACK(0, v0) UNPACK(1, v1) UNPACK(2, v2) UNPACK(3, v3)
      UNPACK(4, v4) UNPACK(5, v5) UNPACK(6, v6) UNPACK(7, v7)
      #undef UNPACK
    }
    __syncthreads();   // sync2: h region ready

    // ---- h chunks kk = 4..19 across 4 accumulator chains ----
    #pragma unroll
    for (int kk = 4; kk < 20; kk += 4) {
      bf16x8 b0 = *(const bf16x8*)(bbase + (((kk + 0) * 64 + kg * 16) ^ bmask));
      a0 = __builtin_amdgcn_mfma_f32_16x16x32_bf16(wfrag[kk + 0], b0, a0, 0, 0, 0);
      bf16x8 b1 = *(const bf16x8*)(bbase + (((kk + 1) * 64 + kg * 16) ^ bmask));
      a1 = __builtin_amdgcn_mfma_f32_16x16x32_bf16(wfrag[kk + 1], b1, a1, 0, 0, 0);
      bf16x8 b2 = *(const bf16x8*)(bbase + (((kk + 2) * 64 + kg * 16) ^ bmask));
      a2 = __builtin_amdgcn_mfma_f32_16x16x32_bf16(wfrag[kk + 2], b2, a2, 0, 0, 0);
      bf16x8 b3 = *(const bf16x8*)(bbase + (((kk + 3) * 64 + kg * 16) ^ bmask));
      a3 = __builtin_amdgcn_mfma_f32_16x16x32_bf16(wfrag[kk + 3], b3, a3, 0, 0, 0);
    }
    f32x4 dsum = (a0 + a1) + (a2 + a3);

    // ---- 4x4 transpose across kg groups -> lane holds 4 gate types ----
    float d0 = dsum[0], d1 = dsum[1], d2 = dsum[2], d3 = dsum[3];
    float t0 = __shfl_xor((kg & 2) ? d0 : d2, 32, 64);
    float t1 = __shfl_xor((kg & 2) ? d1 : d3, 32, 64);
    float w0 = (kg & 2) ? t0 : d0;
    float w1 = (kg & 2) ? t1 : d1;
    float w2 = (kg & 2) ? d2 : t0;
    float w3 = (kg & 2) ? d3 : t1;
    float t2 = __shfl_xor((kg & 1) ? w0 : w1, 16, 64);
    float t3 = __shfl_xor((kg & 1) ? w2 : w3, 16, 64);
    float gi = (kg & 1) ? t2 : w0;
    float gf = (kg & 1) ? w1 : t2;
    float gg = (kg & 1) ? t3 : w2;
    float go = (kg & 1) ? w3 : t3;

    // ---- gate math + state update (1 cell per lane) ----
    float iv = sigm(gi + bi_);
    float fv = sigm(gf + bf_);
    float gv = tanh_f(gg + bg_);
    float ov = sigm(go + bo_);
    c_state = fv * c_state + iv * gv;
    float hv = ov * tanh_f(c_state);

    // ---- publish: lane -> pub tile; kg0 lanes store one dwordx4 per row ----
    u32 val = ((u32)(t + 1) << 16) | bf16bits(hv);
    *(u32*)pub_w = val;
    asm volatile("s_waitcnt lgkmcnt(0)" ::: "memory");   // same-wave RAW order
    __builtin_amdgcn_sched_barrier(0);
    if (kg == 0) {
      u32x4 pv = *(const u32x4*)pub_r;   // this wave's 4 j-words, row fr
      u32* pdst = hbuf + (size_t)((t + 1) & 1) * HSLOT
                + (size_t)(row0 + fr) * H_ + j0 + 4 * wave;
      asm volatile("global_store_dwordx4 %0, %1, off sc0 sc1"
                   :: "v"(pdst), "v"(pv) : "memory");
    }

    if (t == T_ - 1) hf32[(size_t)(row0 + fr) * H_ + jcol] = hv;
  }
}

__global__ void __launch_bounds__(64) out_kernel(
    const float* __restrict__ h_f32,
    const float* __restrict__ Wout,
    const float* __restrict__ bout,
    float* __restrict__ out)
{
  int b = blockIdx.x;
  int lane = threadIdx.x;
  float a0 = 0.f, a1 = 0.f, a2 = 0.f, a3 = 0.f;
  for (int j = lane; j < H_; j += 64) {
    float hv = fmaxf(h_f32[(size_t)b * H_ + j], 0.f);
    a0 += hv * Wout[0 * H_ + j];
    a1 += hv * Wout[1 * H_ + j];
    a2 += hv * Wout[2 * H_ + j];
    a3 += hv * Wout[3 * H_ + j];
  }
  #pragma unroll
  for (int off = 32; off; off >>= 1) {
    a0 += __shfl_down(a0, off);
    a1 += __shfl_down(a1, off);
    a2 += __shfl_down(a2, off);
    a3 += __shfl_down(a3, off);
  }
  if (lane == 0) {
    out[b * 4 + 0] = a0 + bout[0];
    out[b * 4 + 1] = a1 + bout[1];
    out[b * 4 + 2] = a2 + bout[2];
    out[b * 4 + 3] = a3 + bout[3];
  }
}

extern "C" void kernel_launch(void* const* d_in, const int* in_sizes, int n_in,
                              void* d_out, int out_size, void* d_ws, size_t ws_size,
                              hipStream_t stream) {
  const float* x    = (const float*)d_in[0];
  const float* Wih  = (const float*)d_in[1];
  const float* Whh  = (const float*)d_in[2];
  const float* bih  = (const float*)d_in[3];
  const float* bhh  = (const float*)d_in[4];
  // d_in[5..8] = layer-1 weights: dead code in the reference, unused.
  const float* Wout = (const float*)d_in[9];
  const float* bout = (const float*)d_in[10];

  char* ws = (char*)d_ws;
  u32*   hbuf = (u32*)ws;                    // 262144 B
  float* hf32 = (float*)(ws + 262144);       // 131072 B
  const size_t XBF_OFF = 393216;
  const size_t XBF_SZ = (size_t)T_ * 4 * 16 * 128 * 2;   // 33554432 B
  bf16* xbf = (ws_size >= XBF_OFF + XBF_SZ) ? (bf16*)(ws + XBF_OFF) : nullptr;

  hipLaunchKernelGGL(prep_kernel, dim3(256), dim3(NTHR), 0, stream, hbuf);
  if (xbf)
    hipLaunchKernelGGL(xconv_kernel, dim3(64, 8), dim3(NTHR), 0, stream, x, xbf);

  void* args[] = { (void*)&x, (void*)&Wih, (void*)&Whh, (void*)&bih, (void*)&bhh,
                   (void*)&hbuf, (void*)&hf32, (void*)&xbf };
  hipLaunchCooperativeKernel((void*)lstm_kernel, dim3(NBLK), dim3(NTHR),
                             args, 0, stream);

  hipLaunchKernelGGL(out_kernel, dim3(B_), dim3(64), 0, stream,
                     hf32, Wout, bout, (float*)d_out);
}